// Round 3
// baseline (214.456 us; speedup 1.0000x reference)
//
#include <hip/hip_runtime.h>

#define BATCH 2
#define SEQL 1024
#define DMODEL 1024
#define DINNER 2048
#define DSTATE 16
#define DTRANK 64
#define NCH 64
#define LC 16   // SEQL / NCH

typedef short bf16x8 __attribute__((ext_vector_type(8)));
typedef float f32x4 __attribute__((ext_vector_type(4)));
typedef int i32x4 __attribute__((ext_vector_type(4)));

__device__ __forceinline__ unsigned short f2bf(float f) {
  unsigned u = __float_as_uint(f);
  return (unsigned short)((u + 0x7fffu + ((u >> 16) & 1u)) >> 16);
}
__device__ __forceinline__ float sigmoidf_(float x) { return 1.f / (1.f + __expf(-x)); }

__device__ __forceinline__ void gl_lds16(const unsigned short* g, unsigned short* l) {
  __builtin_amdgcn_global_load_lds(
      (const __attribute__((address_space(1))) unsigned int*)g,
      (__attribute__((address_space(3))) unsigned int*)l, 16, 0, 0);
}

// ---------------- m97-structure bf16 MFMA GEMM: C[M][N] (+)= A[M][K] * Bt[N][K]^T ----------------
// mode 0: plain store; mode 1: C = softplus(acc + bias[n]) (only on gridDim.z==1 path)
#define BM 128
#define BN 128

__global__ __launch_bounds__(256) void k_gemm_mfma(
    const unsigned short* __restrict__ A,   // [M][K] bf16 bits
    const unsigned short* __restrict__ Bt,  // [N][K] bf16 bits
    float* __restrict__ C, int M, int N, int K,
    const float* __restrict__ bias, int mode)
{
  __shared__ __attribute__((aligned(16))) unsigned short As[128 * 64];
  __shared__ __attribute__((aligned(16))) unsigned short Bs[128 * 64];
  const int tid = threadIdx.x;
  const int wave = tid >> 6, lane = tid & 63;
  const int m0 = blockIdx.x * BM, n0 = blockIdx.y * BN;
  const int Kc = K / gridDim.z;
  const int k0beg = blockIdx.z * Kc;
  const int wr = (wave >> 1) * 64, wc = (wave & 1) * 64;
  const int fr = lane & 15;
  const int qw = lane >> 4;

  int srow[4], scol[4];
  #pragma unroll
  for (int i = 0; i < 4; ++i) {
    int off = wave * 4096 + i * 1024 + lane * 16;
    int row = off >> 7;                       // 128 B per row (64 bf16)
    int c16 = ((off >> 4) & 7) ^ (row & 7);   // inverse XOR swizzle
    srow[i] = row;
    scol[i] = c16 * 8;                        // in shorts
  }

  f32x4 acc[4][4] = {};
  for (int k0 = k0beg; k0 < k0beg + Kc; k0 += 64) {
    #pragma unroll
    for (int i = 0; i < 4; ++i)
      gl_lds16(A + (size_t)(m0 + srow[i]) * K + k0 + scol[i],
               &As[(wave * 4096 + i * 1024) >> 1]);
    #pragma unroll
    for (int i = 0; i < 4; ++i)
      gl_lds16(Bt + (size_t)(n0 + srow[i]) * K + k0 + scol[i],
               &Bs[(wave * 4096 + i * 1024) >> 1]);
    __syncthreads();
    #pragma unroll
    for (int t = 0; t < 2; ++t) {
      bf16x8 af[4], bfv[4];
      #pragma unroll
      for (int i = 0; i < 4; ++i) {
        int row = wr + i * 16 + fr;
        int c16 = (t * 4 + qw) ^ (row & 7);   // swizzled read
        af[i] = *(const bf16x8*)&As[row * 64 + c16 * 8];
      }
      #pragma unroll
      for (int j = 0; j < 4; ++j) {
        int row = wc + j * 16 + fr;
        int c16 = (t * 4 + qw) ^ (row & 7);
        bfv[j] = *(const bf16x8*)&Bs[row * 64 + c16 * 8];
      }
      #pragma unroll
      for (int i = 0; i < 4; ++i)
        #pragma unroll
        for (int j = 0; j < 4; ++j)
          acc[i][j] = __builtin_amdgcn_mfma_f32_16x16x32_bf16(af[i], bfv[j], acc[i][j], 0, 0, 0);
    }
    __syncthreads();
  }
  const int rr = qw * 4;
  if (gridDim.z == 1) {
    if (mode == 1) {
      #pragma unroll
      for (int j = 0; j < 4; ++j) {
        float bj = bias[n0 + wc + j * 16 + fr];
        #pragma unroll
        for (int i = 0; i < 4; ++i)
          #pragma unroll
          for (int r = 0; r < 4; ++r) {
            float v = acc[i][j][r] + bj;
            C[(size_t)(m0 + wr + i * 16 + rr + r) * N + (n0 + wc + j * 16 + fr)] =
                __logf(1.f + __expf(v));
          }
      }
    } else {
      #pragma unroll
      for (int i = 0; i < 4; ++i)
        #pragma unroll
        for (int j = 0; j < 4; ++j)
          #pragma unroll
          for (int r = 0; r < 4; ++r)
            C[(size_t)(m0 + wr + i * 16 + rr + r) * N + (n0 + wc + j * 16 + fr)] = acc[i][j][r];
    }
  } else {
    #pragma unroll
    for (int i = 0; i < 4; ++i)
      #pragma unroll
      for (int j = 0; j < 4; ++j)
        #pragma unroll
        for (int r = 0; r < 4; ++r)
          atomicAdd(&C[(size_t)(m0 + wr + i * 16 + rr + r) * N + (n0 + wc + j * 16 + fr)],
                    acc[i][j][r]);
  }
}

// ---------------- fp32 -> bf16 flat convert ----------------
__global__ void k_f32_to_bf16(const float* __restrict__ in, unsigned short* __restrict__ out, int n)
{
  int i = (blockIdx.x * 256 + threadIdx.x) * 4;
  if (i >= n) return;
  float4 v = *(const float4*)(in + i);
  unsigned short tmp[4] = {f2bf(v.x), f2bf(v.y), f2bf(v.z), f2bf(v.w)};
  *(unsigned long long*)(out + i) = *(unsigned long long*)tmp;
}

// ---------------- LDS-tiled transpose + convert: src[R][C] f32 -> dst[C][R] bf16 ----------------
__global__ __launch_bounds__(256) void k_transpose_bf16(
    const float* __restrict__ src, unsigned short* __restrict__ dst, int R, int C)
{
  __shared__ float t[64][65];
  int bc = blockIdx.x * 64, br = blockIdx.y * 64;
  int tr = threadIdx.x >> 2;
  int tc = (threadIdx.x & 3) * 16;
  #pragma unroll
  for (int i = 0; i < 4; ++i) {
    float4 v = *(const float4*)(src + (size_t)(br + tr) * C + bc + tc + i * 4);
    t[tr][tc + i * 4 + 0] = v.x; t[tr][tc + i * 4 + 1] = v.y;
    t[tr][tc + i * 4 + 2] = v.z; t[tr][tc + i * 4 + 3] = v.w;
  }
  __syncthreads();
  unsigned short tmp[16];
  #pragma unroll
  for (int i = 0; i < 16; ++i) tmp[i] = f2bf(t[tc + i][tr]);
  unsigned short* dp = dst + (size_t)(bc + tr) * R + br + tc;
  *(i32x4*)dp = *(i32x4*)&tmp[0];
  *(i32x4*)(dp + 8) = *(i32x4*)&tmp[8];
}

// ---------------- W_x (2048x96) -> padded transposed bf16 [128][2048] ----------------
__global__ void k_wx_pad_t(const float* __restrict__ Wx, unsigned short* __restrict__ out)
{
  int idx = blockIdx.x * 256 + threadIdx.x;  // over 128*2048
  int k = idx & (DINNER - 1);
  int n = idx >> 11;
  float v = (n < 96) ? Wx[(size_t)k * 96 + n] : 0.f;
  out[idx] = f2bf(v);
}

// ---------------- depthwise conv4 + bias + SiLU ----------------
__global__ void k_conv_silu(const float* __restrict__ xz, const float* __restrict__ cw,
                            const float* __restrict__ cb, float* __restrict__ xc,
                            unsigned short* __restrict__ xcb)
{
  int idx = blockIdx.x * 256 + threadIdx.x;  // over B*L*DINNER
  int d = idx & (DINNER - 1);
  int bl = idx >> 11;
  int l = bl & (SEQL - 1);
  float s = cb[d];
  #pragma unroll
  for (int k = 0; k < 4; ++k) {
    int ll = l - 3 + k;
    if (ll >= 0) s += xz[(size_t)(bl - 3 + k) * (2 * DINNER) + d] * cw[d * 4 + k];
  }
  float r = s * sigmoidf_(s);
  xc[idx] = r;
  xcb[idx] = f2bf(r);
}

// ---------------- extract dt_raw (cols 0..63 of dbl[2048][128]) -> bf16 ----------------
__global__ void k_extract_dt(const float* __restrict__ dbl, unsigned short* __restrict__ dtraw)
{
  int idx = blockIdx.x * 256 + threadIdx.x;  // 2048*64
  int k = idx & 63;
  int rw = idx >> 6;
  dtraw[idx] = f2bf(dbl[(size_t)rw * 128 + k]);
}

// ---------------- scan pass A: per-chunk local scan (dt precomputed), prefetch-pipelined ----------------
__global__ __launch_bounds__(256) void k_scan_A(
    const float* __restrict__ dtb, const float* __restrict__ xc,
    const float* __restrict__ dbl, const float* __restrict__ Alog,
    float* __restrict__ hend, float* __restrict__ aprod)
{
  int gid = blockIdx.x * 256 + threadIdx.x;  // over B*NCH*DINNER
  int d = gid & (DINNER - 1);
  int t = gid >> 11;
  int c = t & (NCH - 1);
  int b = t >> 6;
  float alf[DSTATE];
  #pragma unroll
  for (int i = 0; i < 4; ++i) *(f32x4*)&alf[i * 4] = *(const f32x4*)&Alog[d * DSTATE + i * 4];
  float As[DSTATE];
  #pragma unroll
  for (int s = 0; s < DSTATE; ++s) As[s] = -__expf(alf[s]);
  float h[DSTATE];
  #pragma unroll
  for (int s = 0; s < DSTATE; ++s) h[s] = 0.f;
  float sumdt = 0.f;
  const int r0 = b * SEQL + c * LC;
  float dtq[2], xvq[2];
  f32x4 Bq[2][4];
  dtq[0] = dtb[(size_t)r0 * DINNER + d];
  xvq[0] = xc[(size_t)r0 * DINNER + d];
  {
    const float* bp = dbl + (size_t)r0 * 128 + 64;
    #pragma unroll
    for (int i = 0; i < 4; ++i) Bq[0][i] = *(const f32x4*)(bp + i * 4);
  }
  #pragma unroll
  for (int li = 0; li < LC; ++li) {
    const int cur = li & 1, nxt = cur ^ 1;
    if (li + 1 < LC) {
      const int rn = r0 + li + 1;
      dtq[nxt] = dtb[(size_t)rn * DINNER + d];
      xvq[nxt] = xc[(size_t)rn * DINNER + d];
      const float* bp = dbl + (size_t)rn * 128 + 64;
      #pragma unroll
      for (int i = 0; i < 4; ++i) Bq[nxt][i] = *(const f32x4*)(bp + i * 4);
    }
    const float dt = dtq[cur], xv = xvq[cur];
    const float dtx = dt * xv;
    sumdt += dt;
    const float* Bv = (const float*)Bq[cur];
    #pragma unroll
    for (int s = 0; s < DSTATE; ++s) {
      float dA = __expf(dt * As[s]);
      h[s] = dA * h[s] + dtx * Bv[s];
    }
  }
  size_t base = ((size_t)(b * NCH + c) * DSTATE) * DINNER + d;
  #pragma unroll
  for (int s = 0; s < DSTATE; ++s) {
    hend[base + (size_t)s * DINNER] = h[s];
    aprod[base + (size_t)s * DINNER] = __expf(sumdt * As[s]);
  }
}

// ---------------- scan pass B: sequential prefix over chunks ----------------
__global__ void k_scan_B(const float* __restrict__ hend, const float* __restrict__ aprod,
                         float* __restrict__ hin)
{
  int gid = blockIdx.x * 256 + threadIdx.x;  // B*DSTATE*DINNER = 65536
  int d = gid & (DINNER - 1);
  int s = (gid >> 11) & (DSTATE - 1);
  int b = gid >> 15;
  float h = 0.f;
  #pragma unroll 8
  for (int c = 0; c < NCH; ++c) {
    size_t idx = ((size_t)(b * NCH + c) * DSTATE + s) * DINNER + d;
    hin[idx] = h;
    h = aprod[idx] * h + hend[idx];
  }
}

// ---------------- scan pass C: replay with correct h_in + fused epilogue, prefetch-pipelined ----------------
__global__ __launch_bounds__(256) void k_scan_C(
    const float* __restrict__ dtb, const float* __restrict__ xc,
    const float* __restrict__ dbl, const float* __restrict__ Alog,
    const float* __restrict__ hin, const float* __restrict__ Dskip,
    const float* __restrict__ xz, unsigned short* __restrict__ yact)
{
  int gid = blockIdx.x * 256 + threadIdx.x;
  int d = gid & (DINNER - 1);
  int t = gid >> 11;
  int c = t & (NCH - 1);
  int b = t >> 6;
  float alf[DSTATE];
  #pragma unroll
  for (int i = 0; i < 4; ++i) *(f32x4*)&alf[i * 4] = *(const f32x4*)&Alog[d * DSTATE + i * 4];
  float As[DSTATE];
  #pragma unroll
  for (int s = 0; s < DSTATE; ++s) As[s] = -__expf(alf[s]);
  float h[DSTATE];
  size_t base = ((size_t)(b * NCH + c) * DSTATE) * DINNER + d;
  #pragma unroll
  for (int s = 0; s < DSTATE; ++s) h[s] = hin[base + (size_t)s * DINNER];
  const float dsk = Dskip[d];
  const int r0 = b * SEQL + c * LC;
  float dtq[2], xvq[2], zvq[2];
  f32x4 Bq[2][4];
  dtq[0] = dtb[(size_t)r0 * DINNER + d];
  xvq[0] = xc[(size_t)r0 * DINNER + d];
  zvq[0] = xz[(size_t)r0 * (2 * DINNER) + DINNER + d];
  {
    const float* bp = dbl + (size_t)r0 * 128 + 64;
    #pragma unroll
    for (int i = 0; i < 4; ++i) Bq[0][i] = *(const f32x4*)(bp + i * 4);
  }
  #pragma unroll
  for (int li = 0; li < LC; ++li) {
    const int cur = li & 1, nxt = cur ^ 1;
    const int r = r0 + li;
    // current step's C row (L1-hot: same cacheline region as B row)
    f32x4 Cq[4];
    {
      const float* cp = dbl + (size_t)r * 128 + 80;
      #pragma unroll
      for (int i = 0; i < 4; ++i) Cq[i] = *(const f32x4*)(cp + i * 4);
    }
    if (li + 1 < LC) {
      const int rn = r + 1;
      dtq[nxt] = dtb[(size_t)rn * DINNER + d];
      xvq[nxt] = xc[(size_t)rn * DINNER + d];
      zvq[nxt] = xz[(size_t)rn * (2 * DINNER) + DINNER + d];
      const float* bp = dbl + (size_t)rn * 128 + 64;
      #pragma unroll
      for (int i = 0; i < 4; ++i) Bq[nxt][i] = *(const f32x4*)(bp + i * 4);
    }
    const float dt = dtq[cur], xv = xvq[cur], zv = zvq[cur];
    const float dtx = dt * xv;
    const float* Bv = (const float*)Bq[cur];
    const float* Cv = (const float*)Cq;
    float y = 0.f;
    #pragma unroll
    for (int s = 0; s < DSTATE; ++s) {
      float dA = __expf(dt * As[s]);
      h[s] = dA * h[s] + dtx * Bv[s];
      y += h[s] * Cv[s];
    }
    y += xv * dsk;
    float ya = y * (zv * sigmoidf_(zv));
    yact[(size_t)r * DINNER + d] = f2bf(ya);
  }
}

extern "C" void kernel_launch(void* const* d_in, const int* in_sizes, int n_in,
                              void* d_out, int out_size, void* d_ws, size_t ws_size,
                              hipStream_t stream) {
  const float* x     = (const float*)d_in[0];
  const float* Win   = (const float*)d_in[1];
  const float* cw    = (const float*)d_in[2];
  const float* cbias = (const float*)d_in[3];
  const float* Wx    = (const float*)d_in[4];
  const float* Wdt   = (const float*)d_in[5];
  const float* bdt   = (const float*)d_in[6];
  const float* Alog  = (const float*)d_in[7];
  const float* Dsk   = (const float*)d_in[8];
  const float* Wout  = (const float*)d_in[9];
  float* out = (float*)d_out;

  char* ws = (char*)d_ws;
  size_t o = 0;
  auto alloc = [&](size_t bytes) { char* p = ws + o; o += (bytes + 255) & ~(size_t)255; return p; };
  float*          xz    = (float*)         alloc((size_t)2048 * 4096 * 4);
  unsigned short* xbf   = (unsigned short*)alloc((size_t)2048 * 1024 * 2);
  unsigned short* wint  = (unsigned short*)alloc((size_t)4096 * 1024 * 2);
  float*          xc    = (float*)         alloc((size_t)2048 * 2048 * 4);
  unsigned short* xcb   = (unsigned short*)alloc((size_t)2048 * 2048 * 2);
  unsigned short* wxt   = (unsigned short*)alloc((size_t)128  * 2048 * 2);
  float*          dbl   = (float*)         alloc((size_t)2048 * 128  * 4);
  unsigned short* dtraw = (unsigned short*)alloc((size_t)2048 * 64   * 2);
  unsigned short* wdtt  = (unsigned short*)alloc((size_t)2048 * 64   * 2);
  float*          dtbuf = (float*)         alloc((size_t)2048 * 2048 * 4);
  float*          hend  = (float*)         alloc((size_t)2 * NCH * DSTATE * DINNER * 4);
  float*          aprod = (float*)         alloc((size_t)2 * NCH * DSTATE * DINNER * 4);
  float*          hin   = (float*)         alloc((size_t)2 * NCH * DSTATE * DINNER * 4);
  unsigned short* yact  = (unsigned short*)alloc((size_t)2048 * 2048 * 2);
  unsigned short* woutt = (unsigned short*)alloc((size_t)1024 * 2048 * 2);
  (void)ws_size; (void)in_sizes; (void)n_in; (void)out_size;

  // convert x -> bf16
  k_f32_to_bf16<<<2048, 256, 0, stream>>>(x, xbf, 2048 * 1024);
  // transpose+convert weights
  k_transpose_bf16<<<dim3(64, 16), 256, 0, stream>>>(Win,  wint,  1024, 4096);  // [4096][1024]
  k_transpose_bf16<<<dim3(16, 32), 256, 0, stream>>>(Wout, woutt, 2048, 1024);  // [1024][2048]
  k_transpose_bf16<<<dim3(32, 1),  256, 0, stream>>>(Wdt,  wdtt,  64,   2048);  // [2048][64]
  k_wx_pad_t<<<1024, 256, 0, stream>>>(Wx, wxt);                                // [128][2048]

  // GEMM1: xz = x @ W_in   (M=2048, N=4096, K=1024)
  k_gemm_mfma<<<dim3(16, 32, 1), 256, 0, stream>>>(xbf, wint, xz, 2048, 4096, 1024, nullptr, 0);
  // conv + SiLU
  k_conv_silu<<<16384, 256, 0, stream>>>(xz, cw, cbias, xc, xcb);
  // GEMM2: dbl = xc @ W_x_pad  (M=2048, N=128, K=2048), split-K=8
  hipMemsetAsync(dbl, 0, (size_t)2048 * 128 * 4, stream);
  k_gemm_mfma<<<dim3(16, 1, 8), 256, 0, stream>>>(xcb, wxt, dbl, 2048, 128, 2048, nullptr, 0);
  // dt_raw extract
  k_extract_dt<<<512, 256, 0, stream>>>(dbl, dtraw);
  // GEMM3 (+fused softplus+bias): dt = softplus(dt_raw @ W_dt + b_dt)  (M=2048, N=2048, K=64)
  k_gemm_mfma<<<dim3(16, 16, 1), 256, 0, stream>>>(dtraw, wdtt, dtbuf, 2048, 2048, 64, bdt, 1);
  // chunked scan
  k_scan_A<<<1024, 256, 0, stream>>>(dtbuf, xc, dbl, Alog, hend, aprod);
  k_scan_B<<<256, 256, 0, stream>>>(hend, aprod, hin);
  k_scan_C<<<1024, 256, 0, stream>>>(dtbuf, xc, dbl, Alog, hin, Dsk, xz, yact);
  // GEMM5: out = y_act @ W_out  (M=2048, N=1024, K=2048), split-K=2
  hipMemsetAsync(out, 0, (size_t)2048 * 1024 * 4, stream);
  k_gemm_mfma<<<dim3(16, 8, 2), 256, 0, stream>>>(yact, woutt, out, 2048, 1024, 2048, nullptr, 0);
}

// Round 4
// 177.627 us; speedup vs baseline: 1.2073x; 1.2073x over previous
//
#include <hip/hip_runtime.h>

#define BATCH 2
#define SEQL 1024
#define DMODEL 1024
#define DINNER 2048
#define DSTATE 16
#define DTRANK 64
#define NCH 64
#define LC 16   // SEQL / NCH

typedef short bf16x8 __attribute__((ext_vector_type(8)));
typedef float f32x4 __attribute__((ext_vector_type(4)));
typedef int i32x4 __attribute__((ext_vector_type(4)));

__device__ __forceinline__ unsigned short f2bf(float f) {
  unsigned u = __float_as_uint(f);
  return (unsigned short)((u + 0x7fffu + ((u >> 16) & 1u)) >> 16);
}
__device__ __forceinline__ float sigmoidf_(float x) { return 1.f / (1.f + __expf(-x)); }

__device__ __forceinline__ void gl_lds16(const unsigned short* g, unsigned short* l) {
  __builtin_amdgcn_global_load_lds(
      (const __attribute__((address_space(1))) unsigned int*)g,
      (__attribute__((address_space(3))) unsigned int*)l, 16, 0, 0);
}

// ---------------- m97-structure bf16 MFMA GEMM: C[M][N] (+)= A[M][K] * Bt[N][K]^T ----------------
// mode 0: plain store; mode 1: C = softplus(acc + bias[n]) (only on gridDim.z==1 path)
#define BM 128
#define BN 128

__global__ __launch_bounds__(256) void k_gemm_mfma(
    const unsigned short* __restrict__ A,   // [M][K] bf16 bits
    const unsigned short* __restrict__ Bt,  // [N][K] bf16 bits
    float* __restrict__ C, int M, int N, int K,
    const float* __restrict__ bias, int mode)
{
  __shared__ __attribute__((aligned(16))) unsigned short As[128 * 64];
  __shared__ __attribute__((aligned(16))) unsigned short Bs[128 * 64];
  const int tid = threadIdx.x;
  const int wave = tid >> 6, lane = tid & 63;
  const int m0 = blockIdx.x * BM, n0 = blockIdx.y * BN;
  const int Kc = K / gridDim.z;
  const int k0beg = blockIdx.z * Kc;
  const int wr = (wave >> 1) * 64, wc = (wave & 1) * 64;
  const int fr = lane & 15;
  const int qw = lane >> 4;

  int srow[4], scol[4];
  #pragma unroll
  for (int i = 0; i < 4; ++i) {
    int off = wave * 4096 + i * 1024 + lane * 16;
    int row = off >> 7;                       // 128 B per row (64 bf16)
    int c16 = ((off >> 4) & 7) ^ (row & 7);   // inverse XOR swizzle
    srow[i] = row;
    scol[i] = c16 * 8;                        // in shorts
  }

  f32x4 acc[4][4] = {};
  for (int k0 = k0beg; k0 < k0beg + Kc; k0 += 64) {
    #pragma unroll
    for (int i = 0; i < 4; ++i)
      gl_lds16(A + (size_t)(m0 + srow[i]) * K + k0 + scol[i],
               &As[(wave * 4096 + i * 1024) >> 1]);
    #pragma unroll
    for (int i = 0; i < 4; ++i)
      gl_lds16(Bt + (size_t)(n0 + srow[i]) * K + k0 + scol[i],
               &Bs[(wave * 4096 + i * 1024) >> 1]);
    __syncthreads();
    #pragma unroll
    for (int t = 0; t < 2; ++t) {
      bf16x8 af[4], bfv[4];
      #pragma unroll
      for (int i = 0; i < 4; ++i) {
        int row = wr + i * 16 + fr;
        int c16 = (t * 4 + qw) ^ (row & 7);   // swizzled read
        af[i] = *(const bf16x8*)&As[row * 64 + c16 * 8];
      }
      #pragma unroll
      for (int j = 0; j < 4; ++j) {
        int row = wc + j * 16 + fr;
        int c16 = (t * 4 + qw) ^ (row & 7);
        bfv[j] = *(const bf16x8*)&Bs[row * 64 + c16 * 8];
      }
      #pragma unroll
      for (int i = 0; i < 4; ++i)
        #pragma unroll
        for (int j = 0; j < 4; ++j)
          acc[i][j] = __builtin_amdgcn_mfma_f32_16x16x32_bf16(af[i], bfv[j], acc[i][j], 0, 0, 0);
    }
    __syncthreads();
  }
  const int rr = qw * 4;
  if (gridDim.z == 1) {
    if (mode == 1) {
      #pragma unroll
      for (int j = 0; j < 4; ++j) {
        float bj = bias[n0 + wc + j * 16 + fr];
        #pragma unroll
        for (int i = 0; i < 4; ++i)
          #pragma unroll
          for (int r = 0; r < 4; ++r) {
            float v = acc[i][j][r] + bj;
            C[(size_t)(m0 + wr + i * 16 + rr + r) * N + (n0 + wc + j * 16 + fr)] =
                __logf(1.f + __expf(v));
          }
      }
    } else {
      #pragma unroll
      for (int i = 0; i < 4; ++i)
        #pragma unroll
        for (int j = 0; j < 4; ++j)
          #pragma unroll
          for (int r = 0; r < 4; ++r)
            C[(size_t)(m0 + wr + i * 16 + rr + r) * N + (n0 + wc + j * 16 + fr)] = acc[i][j][r];
    }
  } else {
    #pragma unroll
    for (int i = 0; i < 4; ++i)
      #pragma unroll
      for (int j = 0; j < 4; ++j)
        #pragma unroll
        for (int r = 0; r < 4; ++r)
          atomicAdd(&C[(size_t)(m0 + wr + i * 16 + rr + r) * N + (n0 + wc + j * 16 + fr)],
                    acc[i][j][r]);
  }
}

// ---------------- fp32 -> bf16 flat convert ----------------
__global__ void k_f32_to_bf16(const float* __restrict__ in, unsigned short* __restrict__ out, int n)
{
  int i = (blockIdx.x * 256 + threadIdx.x) * 4;
  if (i >= n) return;
  float4 v = *(const float4*)(in + i);
  unsigned short tmp[4] = {f2bf(v.x), f2bf(v.y), f2bf(v.z), f2bf(v.w)};
  *(unsigned long long*)(out + i) = *(unsigned long long*)tmp;
}

// ---------------- LDS-tiled transpose + convert: src[R][C] f32 -> dst[C][R] bf16 ----------------
__global__ __launch_bounds__(256) void k_transpose_bf16(
    const float* __restrict__ src, unsigned short* __restrict__ dst, int R, int C)
{
  __shared__ float t[64][65];
  int bc = blockIdx.x * 64, br = blockIdx.y * 64;
  int tr = threadIdx.x >> 2;
  int tc = (threadIdx.x & 3) * 16;
  #pragma unroll
  for (int i = 0; i < 4; ++i) {
    float4 v = *(const float4*)(src + (size_t)(br + tr) * C + bc + tc + i * 4);
    t[tr][tc + i * 4 + 0] = v.x; t[tr][tc + i * 4 + 1] = v.y;
    t[tr][tc + i * 4 + 2] = v.z; t[tr][tc + i * 4 + 3] = v.w;
  }
  __syncthreads();
  unsigned short tmp[16];
  #pragma unroll
  for (int i = 0; i < 16; ++i) tmp[i] = f2bf(t[tc + i][tr]);
  unsigned short* dp = dst + (size_t)(bc + tr) * R + br + tc;
  *(i32x4*)dp = *(i32x4*)&tmp[0];
  *(i32x4*)(dp + 8) = *(i32x4*)&tmp[8];
}

// ---------------- W_x (2048x96) -> padded transposed bf16 [128][2048] ----------------
__global__ void k_wx_pad_t(const float* __restrict__ Wx, unsigned short* __restrict__ out)
{
  int idx = blockIdx.x * 256 + threadIdx.x;  // over 128*2048
  int k = idx & (DINNER - 1);
  int n = idx >> 11;
  float v = (n < 96) ? Wx[(size_t)k * 96 + n] : 0.f;
  out[idx] = f2bf(v);
}

// ---------------- depthwise conv4 + bias + SiLU ----------------
__global__ void k_conv_silu(const float* __restrict__ xz, const float* __restrict__ cw,
                            const float* __restrict__ cb, float* __restrict__ xc,
                            unsigned short* __restrict__ xcb)
{
  int idx = blockIdx.x * 256 + threadIdx.x;  // over B*L*DINNER
  int d = idx & (DINNER - 1);
  int bl = idx >> 11;
  int l = bl & (SEQL - 1);
  float s = cb[d];
  #pragma unroll
  for (int k = 0; k < 4; ++k) {
    int ll = l - 3 + k;
    if (ll >= 0) s += xz[(size_t)(bl - 3 + k) * (2 * DINNER) + d] * cw[d * 4 + k];
  }
  float r = s * sigmoidf_(s);
  xc[idx] = r;
  xcb[idx] = f2bf(r);
}

// ---------------- extract dt_raw (cols 0..63 of dbl[2048][128]) -> bf16 ----------------
__global__ void k_extract_dt(const float* __restrict__ dbl, unsigned short* __restrict__ dtraw)
{
  int idx = blockIdx.x * 256 + threadIdx.x;  // 2048*64
  int k = idx & 63;
  int rw = idx >> 6;
  dtraw[idx] = f2bf(dbl[(size_t)rw * 128 + k]);
}

// ---------------- scan pass A: local scan; B rows via LDS broadcast; 2-step batches ----------------
__global__ __launch_bounds__(256) void k_scan_A(
    const float* __restrict__ dtb, const float* __restrict__ xc,
    const float* __restrict__ dbl, const float* __restrict__ Alog,
    float2* __restrict__ hpair)
{
  __shared__ __attribute__((aligned(16))) float bcB[LC][DSTATE];
  int gid = blockIdx.x * 256 + threadIdx.x;  // over B*NCH*DINNER
  int d = gid & (DINNER - 1);
  int t = gid >> 11;
  int c = t & (NCH - 1);
  int b = t >> 6;
  const int r0 = b * SEQL + c * LC;
  // stage: 16 rows x 16 floats, one float per thread
  bcB[threadIdx.x >> 4][threadIdx.x & 15] =
      dbl[(size_t)(r0 + (threadIdx.x >> 4)) * 128 + 64 + (threadIdx.x & 15)];
  float As[DSTATE];
  #pragma unroll
  for (int i = 0; i < 4; ++i) {
    f32x4 a = *(const f32x4*)&Alog[d * DSTATE + i * 4];
    #pragma unroll
    for (int j = 0; j < 4; ++j) As[i * 4 + j] = -__expf(a[j]);
  }
  __syncthreads();
  float h[DSTATE];
  #pragma unroll
  for (int s = 0; s < DSTATE; ++s) h[s] = 0.f;
  float sumdt = 0.f;
  #pragma unroll
  for (int li = 0; li < LC; li += 2) {
    float dt0 = dtb[(size_t)(r0 + li) * DINNER + d];
    float xv0 = xc [(size_t)(r0 + li) * DINNER + d];
    float dt1 = dtb[(size_t)(r0 + li + 1) * DINNER + d];
    float xv1 = xc [(size_t)(r0 + li + 1) * DINNER + d];
    f32x4 B0[4], B1[4];
    #pragma unroll
    for (int i = 0; i < 4; ++i) B0[i] = *(const f32x4*)&bcB[li][i * 4];
    #pragma unroll
    for (int i = 0; i < 4; ++i) B1[i] = *(const f32x4*)&bcB[li + 1][i * 4];
    float dtx0 = dt0 * xv0, dtx1 = dt1 * xv1;
    sumdt += dt0 + dt1;
    const float* Bv0 = (const float*)B0;
    const float* Bv1 = (const float*)B1;
    #pragma unroll
    for (int s = 0; s < DSTATE; ++s) {
      float dA0 = __expf(dt0 * As[s]);
      h[s] = dA0 * h[s] + dtx0 * Bv0[s];
      float dA1 = __expf(dt1 * As[s]);
      h[s] = dA1 * h[s] + dtx1 * Bv1[s];
    }
  }
  size_t base = ((size_t)(b * NCH + c) * DSTATE) * DINNER + d;
  #pragma unroll
  for (int s = 0; s < DSTATE; ++s) {
    float2 v; v.x = h[s]; v.y = __expf(sumdt * As[s]);
    hpair[base + (size_t)s * DINNER] = v;
  }
}

// ---------------- scan pass B: sequential prefix over chunks, batched loads ----------------
__global__ void k_scan_B(const float2* __restrict__ hpair, float* __restrict__ hin)
{
  int gid = blockIdx.x * 256 + threadIdx.x;  // B*DSTATE*DINNER = 65536
  int d = gid & (DINNER - 1);
  int s = (gid >> 11) & (DSTATE - 1);
  int b = gid >> 15;
  float h = 0.f;
  for (int c0 = 0; c0 < NCH; c0 += 8) {
    float2 v[8];
    #pragma unroll
    for (int i = 0; i < 8; ++i)
      v[i] = hpair[((size_t)(b * NCH + c0 + i) * DSTATE + s) * DINNER + d];
    #pragma unroll
    for (int i = 0; i < 8; ++i) {
      hin[((size_t)(b * NCH + c0 + i) * DSTATE + s) * DINNER + d] = h;
      h = v[i].y * h + v[i].x;
    }
  }
}

// ---------------- scan pass C: replay + fused epilogue; B/C rows via LDS; 2-step batches ----------------
__global__ __launch_bounds__(256) void k_scan_C(
    const float* __restrict__ dtb, const float* __restrict__ xc,
    const float* __restrict__ dbl, const float* __restrict__ Alog,
    const float* __restrict__ hin, const float* __restrict__ Dskip,
    const float* __restrict__ xz, unsigned short* __restrict__ yact)
{
  __shared__ __attribute__((aligned(16))) float bc[LC][32];  // [step][B0..15,C0..15]
  int gid = blockIdx.x * 256 + threadIdx.x;
  int d = gid & (DINNER - 1);
  int t = gid >> 11;
  int c = t & (NCH - 1);
  int b = t >> 6;
  const int r0 = b * SEQL + c * LC;
  {
    int step = threadIdx.x >> 4, j = (threadIdx.x & 15) * 2;
    float2 v = *(const float2*)&dbl[(size_t)(r0 + step) * 128 + 64 + j];
    bc[step][j] = v.x; bc[step][j + 1] = v.y;
  }
  float As[DSTATE];
  #pragma unroll
  for (int i = 0; i < 4; ++i) {
    f32x4 a = *(const f32x4*)&Alog[d * DSTATE + i * 4];
    #pragma unroll
    for (int j = 0; j < 4; ++j) As[i * 4 + j] = -__expf(a[j]);
  }
  float h[DSTATE];
  size_t base = ((size_t)(b * NCH + c) * DSTATE) * DINNER + d;
  #pragma unroll
  for (int s = 0; s < DSTATE; ++s) h[s] = hin[base + (size_t)s * DINNER];
  const float dsk = Dskip[d];
  __syncthreads();
  #pragma unroll
  for (int li = 0; li < LC; li += 2) {
    const int r = r0 + li;
    float dt0 = dtb[(size_t)r * DINNER + d];
    float xv0 = xc [(size_t)r * DINNER + d];
    float zv0 = xz [(size_t)r * (2 * DINNER) + DINNER + d];
    float dt1 = dtb[(size_t)(r + 1) * DINNER + d];
    float xv1 = xc [(size_t)(r + 1) * DINNER + d];
    float zv1 = xz [(size_t)(r + 1) * (2 * DINNER) + DINNER + d];
    f32x4 B0[4], C0[4], B1[4], C1[4];
    #pragma unroll
    for (int i = 0; i < 4; ++i) B0[i] = *(const f32x4*)&bc[li][i * 4];
    #pragma unroll
    for (int i = 0; i < 4; ++i) C0[i] = *(const f32x4*)&bc[li][16 + i * 4];
    #pragma unroll
    for (int i = 0; i < 4; ++i) B1[i] = *(const f32x4*)&bc[li + 1][i * 4];
    #pragma unroll
    for (int i = 0; i < 4; ++i) C1[i] = *(const f32x4*)&bc[li + 1][16 + i * 4];
    const float* Bv0 = (const float*)B0; const float* Cv0 = (const float*)C0;
    const float* Bv1 = (const float*)B1; const float* Cv1 = (const float*)C1;
    float dtx0 = dt0 * xv0, dtx1 = dt1 * xv1;
    float y0 = 0.f, y1 = 0.f;
    #pragma unroll
    for (int s = 0; s < DSTATE; ++s) {
      float dA0 = __expf(dt0 * As[s]);
      h[s] = dA0 * h[s] + dtx0 * Bv0[s];
      y0 += h[s] * Cv0[s];
      float dA1 = __expf(dt1 * As[s]);
      h[s] = dA1 * h[s] + dtx1 * Bv1[s];
      y1 += h[s] * Cv1[s];
    }
    y0 += xv0 * dsk;
    y1 += xv1 * dsk;
    float ya0 = y0 * (zv0 * sigmoidf_(zv0));
    float ya1 = y1 * (zv1 * sigmoidf_(zv1));
    yact[(size_t)r * DINNER + d] = f2bf(ya0);
    yact[(size_t)(r + 1) * DINNER + d] = f2bf(ya1);
  }
}

extern "C" void kernel_launch(void* const* d_in, const int* in_sizes, int n_in,
                              void* d_out, int out_size, void* d_ws, size_t ws_size,
                              hipStream_t stream) {
  const float* x     = (const float*)d_in[0];
  const float* Win   = (const float*)d_in[1];
  const float* cw    = (const float*)d_in[2];
  const float* cbias = (const float*)d_in[3];
  const float* Wx    = (const float*)d_in[4];
  const float* Wdt   = (const float*)d_in[5];
  const float* bdt   = (const float*)d_in[6];
  const float* Alog  = (const float*)d_in[7];
  const float* Dsk   = (const float*)d_in[8];
  const float* Wout  = (const float*)d_in[9];
  float* out = (float*)d_out;

  char* ws = (char*)d_ws;
  size_t o = 0;
  auto alloc = [&](size_t bytes) { char* p = ws + o; o += (bytes + 255) & ~(size_t)255; return p; };
  float*          xz    = (float*)         alloc((size_t)2048 * 4096 * 4);
  unsigned short* xbf   = (unsigned short*)alloc((size_t)2048 * 1024 * 2);
  unsigned short* wint  = (unsigned short*)alloc((size_t)4096 * 1024 * 2);
  float*          xc    = (float*)         alloc((size_t)2048 * 2048 * 4);
  unsigned short* xcb   = (unsigned short*)alloc((size_t)2048 * 2048 * 2);
  unsigned short* wxt   = (unsigned short*)alloc((size_t)128  * 2048 * 2);
  float*          dbl   = (float*)         alloc((size_t)2048 * 128  * 4);
  unsigned short* dtraw = (unsigned short*)alloc((size_t)2048 * 64   * 2);
  unsigned short* wdtt  = (unsigned short*)alloc((size_t)2048 * 64   * 2);
  float*          dtbuf = (float*)         alloc((size_t)2048 * 2048 * 4);
  float2*         hpair = (float2*)        alloc((size_t)2 * NCH * DSTATE * DINNER * 8);
  float*          hin   = (float*)         alloc((size_t)2 * NCH * DSTATE * DINNER * 4);
  unsigned short* yact  = (unsigned short*)alloc((size_t)2048 * 2048 * 2);
  unsigned short* woutt = (unsigned short*)alloc((size_t)1024 * 2048 * 2);
  (void)ws_size; (void)in_sizes; (void)n_in; (void)out_size;

  // convert x -> bf16
  k_f32_to_bf16<<<2048, 256, 0, stream>>>(x, xbf, 2048 * 1024);
  // transpose+convert weights
  k_transpose_bf16<<<dim3(64, 16), 256, 0, stream>>>(Win,  wint,  1024, 4096);  // [4096][1024]
  k_transpose_bf16<<<dim3(16, 32), 256, 0, stream>>>(Wout, woutt, 2048, 1024);  // [1024][2048]
  k_transpose_bf16<<<dim3(32, 1),  256, 0, stream>>>(Wdt,  wdtt,  64,   2048);  // [2048][64]
  k_wx_pad_t<<<1024, 256, 0, stream>>>(Wx, wxt);                                // [128][2048]

  // GEMM1: xz = x @ W_in   (M=2048, N=4096, K=1024)
  k_gemm_mfma<<<dim3(16, 32, 1), 256, 0, stream>>>(xbf, wint, xz, 2048, 4096, 1024, nullptr, 0);
  // conv + SiLU
  k_conv_silu<<<16384, 256, 0, stream>>>(xz, cw, cbias, xc, xcb);
  // GEMM2: dbl = xc @ W_x_pad  (M=2048, N=128, K=2048), split-K=8
  hipMemsetAsync(dbl, 0, (size_t)2048 * 128 * 4, stream);
  k_gemm_mfma<<<dim3(16, 1, 8), 256, 0, stream>>>(xcb, wxt, dbl, 2048, 128, 2048, nullptr, 0);
  // dt_raw extract
  k_extract_dt<<<512, 256, 0, stream>>>(dbl, dtraw);
  // GEMM3 (+fused softplus+bias): dt = softplus(dt_raw @ W_dt + b_dt)  (M=2048, N=2048, K=64)
  k_gemm_mfma<<<dim3(16, 16, 1), 256, 0, stream>>>(dtraw, wdtt, dtbuf, 2048, 2048, 64, bdt, 1);
  // chunked scan
  k_scan_A<<<1024, 256, 0, stream>>>(dtbuf, xc, dbl, Alog, hpair);
  k_scan_B<<<256, 256, 0, stream>>>(hpair, hin);
  k_scan_C<<<1024, 256, 0, stream>>>(dtbuf, xc, dbl, Alog, hin, Dsk, xz, yact);
  // GEMM5: out = y_act @ W_out  (M=2048, N=1024, K=2048), split-K=2
  hipMemsetAsync(out, 0, (size_t)2048 * 1024 * 4, stream);
  k_gemm_mfma<<<dim3(16, 8, 2), 256, 0, stream>>>(yact, woutt, out, 2048, 1024, 2048, nullptr, 0);
}

// Round 5
// 166.332 us; speedup vs baseline: 1.2893x; 1.0679x over previous
//
#include <hip/hip_runtime.h>

#define BATCH 2
#define SEQL 1024
#define DMODEL 1024
#define DINNER 2048
#define DSTATE 16
#define DTRANK 64
#define NCH 64
#define LC 16   // SEQL / NCH

typedef short bf16x8 __attribute__((ext_vector_type(8)));
typedef float f32x4 __attribute__((ext_vector_type(4)));
typedef int i32x4 __attribute__((ext_vector_type(4)));

__device__ __forceinline__ unsigned short f2bf(float f) {
  unsigned u = __float_as_uint(f);
  return (unsigned short)((u + 0x7fffu + ((u >> 16) & 1u)) >> 16);
}
__device__ __forceinline__ float sigmoidf_(float x) { return 1.f / (1.f + __expf(-x)); }

__device__ __forceinline__ void gl_lds16(const unsigned short* g, unsigned short* l) {
  __builtin_amdgcn_global_load_lds(
      (const __attribute__((address_space(1))) unsigned int*)g,
      (__attribute__((address_space(3))) unsigned int*)l, 16, 0, 0);
}

// ---------------- m97-structure bf16 MFMA GEMM: C[M][N] = A[M][K] * Bt[N][K]^T ----------------
// mode 0: plain store; mode 1: C = softplus(acc + bias[n]).
// gridDim.z > 1: K split; each z writes its own slice C[z*M*N + ...] (no atomics).
#define BM 128
#define BN 128

__global__ __launch_bounds__(256) void k_gemm_mfma(
    const unsigned short* __restrict__ A,   // [M][K] bf16 bits
    const unsigned short* __restrict__ Bt,  // [N][K] bf16 bits
    float* __restrict__ C, int M, int N, int K,
    const float* __restrict__ bias, int mode)
{
  __shared__ __attribute__((aligned(16))) unsigned short As[128 * 64];
  __shared__ __attribute__((aligned(16))) unsigned short Bs[128 * 64];
  const int tid = threadIdx.x;
  const int wave = tid >> 6, lane = tid & 63;
  const int m0 = blockIdx.x * BM, n0 = blockIdx.y * BN;
  const int Kc = K / gridDim.z;
  const int k0beg = blockIdx.z * Kc;
  float* Cz = C + (size_t)blockIdx.z * M * N;
  const int wr = (wave >> 1) * 64, wc = (wave & 1) * 64;
  const int fr = lane & 15;
  const int qw = lane >> 4;

  int srow[4], scol[4];
  #pragma unroll
  for (int i = 0; i < 4; ++i) {
    int off = wave * 4096 + i * 1024 + lane * 16;
    int row = off >> 7;                       // 128 B per row (64 bf16)
    int c16 = ((off >> 4) & 7) ^ (row & 7);   // inverse XOR swizzle
    srow[i] = row;
    scol[i] = c16 * 8;                        // in shorts
  }

  f32x4 acc[4][4] = {};
  for (int k0 = k0beg; k0 < k0beg + Kc; k0 += 64) {
    #pragma unroll
    for (int i = 0; i < 4; ++i)
      gl_lds16(A + (size_t)(m0 + srow[i]) * K + k0 + scol[i],
               &As[(wave * 4096 + i * 1024) >> 1]);
    #pragma unroll
    for (int i = 0; i < 4; ++i)
      gl_lds16(Bt + (size_t)(n0 + srow[i]) * K + k0 + scol[i],
               &Bs[(wave * 4096 + i * 1024) >> 1]);
    __syncthreads();
    #pragma unroll
    for (int t = 0; t < 2; ++t) {
      bf16x8 af[4], bfv[4];
      #pragma unroll
      for (int i = 0; i < 4; ++i) {
        int row = wr + i * 16 + fr;
        int c16 = (t * 4 + qw) ^ (row & 7);   // swizzled read
        af[i] = *(const bf16x8*)&As[row * 64 + c16 * 8];
      }
      #pragma unroll
      for (int j = 0; j < 4; ++j) {
        int row = wc + j * 16 + fr;
        int c16 = (t * 4 + qw) ^ (row & 7);
        bfv[j] = *(const bf16x8*)&Bs[row * 64 + c16 * 8];
      }
      #pragma unroll
      for (int i = 0; i < 4; ++i)
        #pragma unroll
        for (int j = 0; j < 4; ++j)
          acc[i][j] = __builtin_amdgcn_mfma_f32_16x16x32_bf16(af[i], bfv[j], acc[i][j], 0, 0, 0);
    }
    __syncthreads();
  }
  const int rr = qw * 4;
  if (mode == 1) {
    #pragma unroll
    for (int j = 0; j < 4; ++j) {
      float bj = bias[n0 + wc + j * 16 + fr];
      #pragma unroll
      for (int i = 0; i < 4; ++i)
        #pragma unroll
        for (int r = 0; r < 4; ++r) {
          float v = acc[i][j][r] + bj;
          Cz[(size_t)(m0 + wr + i * 16 + rr + r) * N + (n0 + wc + j * 16 + fr)] =
              __logf(1.f + __expf(v));
        }
    }
  } else {
    #pragma unroll
    for (int i = 0; i < 4; ++i)
      #pragma unroll
      for (int j = 0; j < 4; ++j)
        #pragma unroll
        for (int r = 0; r < 4; ++r)
          Cz[(size_t)(m0 + wr + i * 16 + rr + r) * N + (n0 + wc + j * 16 + fr)] = acc[i][j][r];
  }
}

// ---------------- reduce 8 split-K partials -> dbl fp32; fuse dt-col extract -> bf16 ----------------
__global__ void k_reduce2(const float* __restrict__ part, float* __restrict__ dbl,
                          unsigned short* __restrict__ dtraw)
{
  int idx = blockIdx.x * 256 + threadIdx.x;  // over 2048*128
  float s = 0.f;
  #pragma unroll
  for (int z = 0; z < 8; ++z) s += part[(size_t)z * 2048 * 128 + idx];
  dbl[idx] = s;
  int col = idx & 127, rw = idx >> 7;
  if (col < 64) dtraw[rw * 64 + col] = f2bf(s);
}

// ---------------- reduce 2 split-K partials -> out (vectorized) ----------------
__global__ void k_reduce5(const float* __restrict__ part, float* __restrict__ out)
{
  int idx = (blockIdx.x * 256 + threadIdx.x) * 4;  // over 2048*1024
  f32x4 a = *(const f32x4*)(part + idx);
  f32x4 b = *(const f32x4*)(part + (size_t)2048 * 1024 + idx);
  *(f32x4*)(out + idx) = a + b;
}

// ---------------- fp32 -> bf16 flat convert ----------------
__global__ void k_f32_to_bf16(const float* __restrict__ in, unsigned short* __restrict__ out, int n)
{
  int i = (blockIdx.x * 256 + threadIdx.x) * 4;
  if (i >= n) return;
  float4 v = *(const float4*)(in + i);
  unsigned short tmp[4] = {f2bf(v.x), f2bf(v.y), f2bf(v.z), f2bf(v.w)};
  *(unsigned long long*)(out + i) = *(unsigned long long*)tmp;
}

// ---------------- LDS-tiled transpose + convert: src[R][C] f32 -> dst[C][R] bf16 ----------------
__global__ __launch_bounds__(256) void k_transpose_bf16(
    const float* __restrict__ src, unsigned short* __restrict__ dst, int R, int C)
{
  __shared__ float t[64][65];
  int bc = blockIdx.x * 64, br = blockIdx.y * 64;
  int tr = threadIdx.x >> 2;
  int tc = (threadIdx.x & 3) * 16;
  #pragma unroll
  for (int i = 0; i < 4; ++i) {
    float4 v = *(const float4*)(src + (size_t)(br + tr) * C + bc + tc + i * 4);
    t[tr][tc + i * 4 + 0] = v.x; t[tr][tc + i * 4 + 1] = v.y;
    t[tr][tc + i * 4 + 2] = v.z; t[tr][tc + i * 4 + 3] = v.w;
  }
  __syncthreads();
  unsigned short tmp[16];
  #pragma unroll
  for (int i = 0; i < 16; ++i) tmp[i] = f2bf(t[tc + i][tr]);
  unsigned short* dp = dst + (size_t)(bc + tr) * R + br + tc;
  *(i32x4*)dp = *(i32x4*)&tmp[0];
  *(i32x4*)(dp + 8) = *(i32x4*)&tmp[8];
}

// ---------------- W_x (2048x96) -> padded transposed bf16 [128][2048] ----------------
__global__ void k_wx_pad_t(const float* __restrict__ Wx, unsigned short* __restrict__ out)
{
  int idx = blockIdx.x * 256 + threadIdx.x;  // over 128*2048
  int k = idx & (DINNER - 1);
  int n = idx >> 11;
  float v = (n < 96) ? Wx[(size_t)k * 96 + n] : 0.f;
  out[idx] = f2bf(v);
}

// ---------------- depthwise conv4 + bias + SiLU ----------------
__global__ void k_conv_silu(const float* __restrict__ xz, const float* __restrict__ cw,
                            const float* __restrict__ cb, float* __restrict__ xc,
                            unsigned short* __restrict__ xcb)
{
  int idx = blockIdx.x * 256 + threadIdx.x;  // over B*L*DINNER
  int d = idx & (DINNER - 1);
  int bl = idx >> 11;
  int l = bl & (SEQL - 1);
  float s = cb[d];
  #pragma unroll
  for (int k = 0; k < 4; ++k) {
    int ll = l - 3 + k;
    if (ll >= 0) s += xz[(size_t)(bl - 3 + k) * (2 * DINNER) + d] * cw[d * 4 + k];
  }
  float r = s * sigmoidf_(s);
  xc[idx] = r;
  xcb[idx] = f2bf(r);
}

// ---------------- scan pass A: local scan; B rows via LDS broadcast; 2-step batches ----------------
__global__ __launch_bounds__(256) void k_scan_A(
    const float* __restrict__ dtb, const float* __restrict__ xc,
    const float* __restrict__ dbl, const float* __restrict__ Alog,
    float2* __restrict__ hpair)
{
  __shared__ __attribute__((aligned(16))) float bcB[LC][DSTATE];
  int gid = blockIdx.x * 256 + threadIdx.x;  // over B*NCH*DINNER
  int d = gid & (DINNER - 1);
  int t = gid >> 11;
  int c = t & (NCH - 1);
  int b = t >> 6;
  const int r0 = b * SEQL + c * LC;
  bcB[threadIdx.x >> 4][threadIdx.x & 15] =
      dbl[(size_t)(r0 + (threadIdx.x >> 4)) * 128 + 64 + (threadIdx.x & 15)];
  float As[DSTATE];
  #pragma unroll
  for (int i = 0; i < 4; ++i) {
    f32x4 a = *(const f32x4*)&Alog[d * DSTATE + i * 4];
    #pragma unroll
    for (int j = 0; j < 4; ++j) As[i * 4 + j] = -__expf(a[j]);
  }
  __syncthreads();
  float h[DSTATE];
  #pragma unroll
  for (int s = 0; s < DSTATE; ++s) h[s] = 0.f;
  float sumdt = 0.f;
  #pragma unroll
  for (int li = 0; li < LC; li += 2) {
    float dt0 = dtb[(size_t)(r0 + li) * DINNER + d];
    float xv0 = xc [(size_t)(r0 + li) * DINNER + d];
    float dt1 = dtb[(size_t)(r0 + li + 1) * DINNER + d];
    float xv1 = xc [(size_t)(r0 + li + 1) * DINNER + d];
    f32x4 B0[4], B1[4];
    #pragma unroll
    for (int i = 0; i < 4; ++i) B0[i] = *(const f32x4*)&bcB[li][i * 4];
    #pragma unroll
    for (int i = 0; i < 4; ++i) B1[i] = *(const f32x4*)&bcB[li + 1][i * 4];
    float dtx0 = dt0 * xv0, dtx1 = dt1 * xv1;
    sumdt += dt0 + dt1;
    const float* Bv0 = (const float*)B0;
    const float* Bv1 = (const float*)B1;
    #pragma unroll
    for (int s = 0; s < DSTATE; ++s) {
      float dA0 = __expf(dt0 * As[s]);
      h[s] = dA0 * h[s] + dtx0 * Bv0[s];
      float dA1 = __expf(dt1 * As[s]);
      h[s] = dA1 * h[s] + dtx1 * Bv1[s];
    }
  }
  size_t base = ((size_t)(b * NCH + c) * DSTATE) * DINNER + d;
  #pragma unroll
  for (int s = 0; s < DSTATE; ++s) {
    float2 v; v.x = h[s]; v.y = __expf(sumdt * As[s]);
    hpair[base + (size_t)s * DINNER] = v;
  }
}

// ---------------- scan pass B: sequential prefix over chunks, batched loads ----------------
__global__ void k_scan_B(const float2* __restrict__ hpair, float* __restrict__ hin)
{
  int gid = blockIdx.x * 256 + threadIdx.x;  // B*DSTATE*DINNER = 65536
  int d = gid & (DINNER - 1);
  int s = (gid >> 11) & (DSTATE - 1);
  int b = gid >> 15;
  float h = 0.f;
  for (int c0 = 0; c0 < NCH; c0 += 8) {
    float2 v[8];
    #pragma unroll
    for (int i = 0; i < 8; ++i)
      v[i] = hpair[((size_t)(b * NCH + c0 + i) * DSTATE + s) * DINNER + d];
    #pragma unroll
    for (int i = 0; i < 8; ++i) {
      hin[((size_t)(b * NCH + c0 + i) * DSTATE + s) * DINNER + d] = h;
      h = v[i].y * h + v[i].x;
    }
  }
}

// ---------------- scan pass C: replay + fused epilogue; B/C rows via LDS; 2-step batches ----------------
__global__ __launch_bounds__(256) void k_scan_C(
    const float* __restrict__ dtb, const float* __restrict__ xc,
    const float* __restrict__ dbl, const float* __restrict__ Alog,
    const float* __restrict__ hin, const float* __restrict__ Dskip,
    const float* __restrict__ xz, unsigned short* __restrict__ yact)
{
  __shared__ __attribute__((aligned(16))) float bc[LC][32];  // [step][B0..15,C0..15]
  int gid = blockIdx.x * 256 + threadIdx.x;
  int d = gid & (DINNER - 1);
  int t = gid >> 11;
  int c = t & (NCH - 1);
  int b = t >> 6;
  const int r0 = b * SEQL + c * LC;
  {
    int step = threadIdx.x >> 4, j = (threadIdx.x & 15) * 2;
    float2 v = *(const float2*)&dbl[(size_t)(r0 + step) * 128 + 64 + j];
    bc[step][j] = v.x; bc[step][j + 1] = v.y;
  }
  float As[DSTATE];
  #pragma unroll
  for (int i = 0; i < 4; ++i) {
    f32x4 a = *(const f32x4*)&Alog[d * DSTATE + i * 4];
    #pragma unroll
    for (int j = 0; j < 4; ++j) As[i * 4 + j] = -__expf(a[j]);
  }
  float h[DSTATE];
  size_t base = ((size_t)(b * NCH + c) * DSTATE) * DINNER + d;
  #pragma unroll
  for (int s = 0; s < DSTATE; ++s) h[s] = hin[base + (size_t)s * DINNER];
  const float dsk = Dskip[d];
  __syncthreads();
  #pragma unroll
  for (int li = 0; li < LC; li += 2) {
    const int r = r0 + li;
    float dt0 = dtb[(size_t)r * DINNER + d];
    float xv0 = xc [(size_t)r * DINNER + d];
    float zv0 = xz [(size_t)r * (2 * DINNER) + DINNER + d];
    float dt1 = dtb[(size_t)(r + 1) * DINNER + d];
    float xv1 = xc [(size_t)(r + 1) * DINNER + d];
    float zv1 = xz [(size_t)(r + 1) * (2 * DINNER) + DINNER + d];
    f32x4 B0[4], C0[4], B1[4], C1[4];
    #pragma unroll
    for (int i = 0; i < 4; ++i) B0[i] = *(const f32x4*)&bc[li][i * 4];
    #pragma unroll
    for (int i = 0; i < 4; ++i) C0[i] = *(const f32x4*)&bc[li][16 + i * 4];
    #pragma unroll
    for (int i = 0; i < 4; ++i) B1[i] = *(const f32x4*)&bc[li + 1][i * 4];
    #pragma unroll
    for (int i = 0; i < 4; ++i) C1[i] = *(const f32x4*)&bc[li + 1][16 + i * 4];
    const float* Bv0 = (const float*)B0; const float* Cv0 = (const float*)C0;
    const float* Bv1 = (const float*)B1; const float* Cv1 = (const float*)C1;
    float dtx0 = dt0 * xv0, dtx1 = dt1 * xv1;
    float y0 = 0.f, y1 = 0.f;
    #pragma unroll
    for (int s = 0; s < DSTATE; ++s) {
      float dA0 = __expf(dt0 * As[s]);
      h[s] = dA0 * h[s] + dtx0 * Bv0[s];
      y0 += h[s] * Cv0[s];
      float dA1 = __expf(dt1 * As[s]);
      h[s] = dA1 * h[s] + dtx1 * Bv1[s];
      y1 += h[s] * Cv1[s];
    }
    y0 += xv0 * dsk;
    y1 += xv1 * dsk;
    float ya0 = y0 * (zv0 * sigmoidf_(zv0));
    float ya1 = y1 * (zv1 * sigmoidf_(zv1));
    yact[(size_t)r * DINNER + d] = f2bf(ya0);
    yact[(size_t)(r + 1) * DINNER + d] = f2bf(ya1);
  }
}

extern "C" void kernel_launch(void* const* d_in, const int* in_sizes, int n_in,
                              void* d_out, int out_size, void* d_ws, size_t ws_size,
                              hipStream_t stream) {
  const float* x     = (const float*)d_in[0];
  const float* Win   = (const float*)d_in[1];
  const float* cw    = (const float*)d_in[2];
  const float* cbias = (const float*)d_in[3];
  const float* Wx    = (const float*)d_in[4];
  const float* Wdt   = (const float*)d_in[5];
  const float* bdt   = (const float*)d_in[6];
  const float* Alog  = (const float*)d_in[7];
  const float* Dsk   = (const float*)d_in[8];
  const float* Wout  = (const float*)d_in[9];
  float* out = (float*)d_out;

  char* ws = (char*)d_ws;
  size_t o = 0;
  auto alloc = [&](size_t bytes) { char* p = ws + o; o += (bytes + 255) & ~(size_t)255; return p; };
  float*          xz    = (float*)         alloc((size_t)2048 * 4096 * 4);
  unsigned short* xbf   = (unsigned short*)alloc((size_t)2048 * 1024 * 2);
  unsigned short* wint  = (unsigned short*)alloc((size_t)4096 * 1024 * 2);
  float*          xc    = (float*)         alloc((size_t)2048 * 2048 * 4);
  unsigned short* xcb   = (unsigned short*)alloc((size_t)2048 * 2048 * 2);
  unsigned short* wxt   = (unsigned short*)alloc((size_t)128  * 2048 * 2);
  float*          dbl   = (float*)         alloc((size_t)2048 * 128  * 4);
  unsigned short* dtraw = (unsigned short*)alloc((size_t)2048 * 64   * 2);
  unsigned short* wdtt  = (unsigned short*)alloc((size_t)2048 * 64   * 2);
  float*          dtbuf = (float*)         alloc((size_t)2048 * 2048 * 4);  // 16 MB; also aliased as split-K partials
  float2*         hpair = (float2*)        alloc((size_t)2 * NCH * DSTATE * DINNER * 8);
  float*          hin   = (float*)         alloc((size_t)2 * NCH * DSTATE * DINNER * 4);
  unsigned short* yact  = (unsigned short*)alloc((size_t)2048 * 2048 * 2);
  unsigned short* woutt = (unsigned short*)alloc((size_t)1024 * 2048 * 2);
  // aliases (lifetimes strictly sequential on one stream):
  float* part2 = dtbuf;  // 8 x 2048*128 = 8 MB, dead before GEMM3 writes dtbuf
  float* part5 = dtbuf;  // 2 x 2048*1024 = 16 MB, used after scan_C retires dtbuf
  (void)ws_size; (void)in_sizes; (void)n_in; (void)out_size;

  // convert x -> bf16
  k_f32_to_bf16<<<2048, 256, 0, stream>>>(x, xbf, 2048 * 1024);
  // transpose+convert weights
  k_transpose_bf16<<<dim3(64, 16), 256, 0, stream>>>(Win,  wint,  1024, 4096);  // [4096][1024]
  k_transpose_bf16<<<dim3(16, 32), 256, 0, stream>>>(Wout, woutt, 2048, 1024);  // [1024][2048]
  k_transpose_bf16<<<dim3(32, 1),  256, 0, stream>>>(Wdt,  wdtt,  64,   2048);  // [2048][64]
  k_wx_pad_t<<<1024, 256, 0, stream>>>(Wx, wxt);                                // [128][2048]

  // GEMM1: xz = x @ W_in   (M=2048, N=4096, K=1024)
  k_gemm_mfma<<<dim3(16, 32, 1), 256, 0, stream>>>(xbf, wint, xz, 2048, 4096, 1024, nullptr, 0);
  // conv + SiLU
  k_conv_silu<<<16384, 256, 0, stream>>>(xz, cw, cbias, xc, xcb);
  // GEMM2: part2[z] = xc @ W_x_pad (K-slice z)  (M=2048, N=128, K=2048, split 8)
  k_gemm_mfma<<<dim3(16, 1, 8), 256, 0, stream>>>(xcb, wxt, part2, 2048, 128, 2048, nullptr, 0);
  // reduce partials -> dbl; fused dt-col extract -> bf16
  k_reduce2<<<1024, 256, 0, stream>>>(part2, dbl, dtraw);
  // GEMM3 (+fused softplus+bias): dt = softplus(dt_raw @ W_dt + b_dt)  (M=2048, N=2048, K=64)
  k_gemm_mfma<<<dim3(16, 16, 1), 256, 0, stream>>>(dtraw, wdtt, dtbuf, 2048, 2048, 64, bdt, 1);
  // chunked scan
  k_scan_A<<<1024, 256, 0, stream>>>(dtbuf, xc, dbl, Alog, hpair);
  k_scan_B<<<256, 256, 0, stream>>>(hpair, hin);
  k_scan_C<<<1024, 256, 0, stream>>>(dtbuf, xc, dbl, Alog, hin, Dsk, xz, yact);
  // GEMM5: part5[z] = y_act @ W_out (K-slice z)  (M=2048, N=1024, K=2048, split 2)
  k_gemm_mfma<<<dim3(16, 8, 2), 256, 0, stream>>>(yact, woutt, part5, 2048, 1024, 2048, nullptr, 0);
  // reduce partials -> out
  k_reduce5<<<2048, 256, 0, stream>>>(part5, out);
}

// Round 7
// 151.509 us; speedup vs baseline: 1.4155x; 1.0978x over previous
//
#include <hip/hip_runtime.h>

#define BATCH 2
#define SEQL 1024
#define DMODEL 1024
#define DINNER 2048
#define DSTATE 16
#define DTRANK 64
#define NCH 64
#define LC 16   // SEQL / NCH

typedef short bf16x8 __attribute__((ext_vector_type(8)));
typedef float f32x4 __attribute__((ext_vector_type(4)));
typedef int i32x4 __attribute__((ext_vector_type(4)));

__device__ __forceinline__ unsigned short f2bf(float f) {
  unsigned u = __float_as_uint(f);
  return (unsigned short)((u + 0x7fffu + ((u >> 16) & 1u)) >> 16);
}
__device__ __forceinline__ float bf2f(unsigned short u) {
  return __uint_as_float((unsigned)u << 16);
}
__device__ __forceinline__ float sigmoidf_(float x) { return 1.f / (1.f + __expf(-x)); }

__device__ __forceinline__ void gl_lds16(const unsigned short* g, unsigned short* l) {
  __builtin_amdgcn_global_load_lds(
      (const __attribute__((address_space(1))) unsigned int*)g,
      (__attribute__((address_space(3))) unsigned int*)l, 16, 0, 0);
}

// ---------------- m97-structure bf16 MFMA GEMM: A[M][K] * Bt[N][K]^T ----------------
// mode 0: fp32 partials, slice per blockIdx.z (split-K, no atomics)
// mode 1: C2 = bf16(softplus(acc + bias[n]))
// mode 2: cols<2048 -> C fp32 (stride 2048); cols>=2048 -> C2 bf16 (stride 2048)
#define BM 128
#define BN 128

__global__ __launch_bounds__(256) void k_gemm_mfma(
    const unsigned short* __restrict__ A,   // [M][K] bf16 bits
    const unsigned short* __restrict__ Bt,  // [N][K] bf16 bits
    float* __restrict__ C, unsigned short* __restrict__ C2,
    int M, int N, int K, const float* __restrict__ bias, int mode)
{
  __shared__ __attribute__((aligned(16))) unsigned short As[128 * 64];
  __shared__ __attribute__((aligned(16))) unsigned short Bs[128 * 64];
  const int tid = threadIdx.x;
  const int wave = tid >> 6, lane = tid & 63;
  const int m0 = blockIdx.x * BM, n0 = blockIdx.y * BN;
  const int Kc = K / gridDim.z;
  const int k0beg = blockIdx.z * Kc;
  float* Cz = C + (size_t)blockIdx.z * M * N;
  const int wr = (wave >> 1) * 64, wc = (wave & 1) * 64;
  const int fr = lane & 15;
  const int qw = lane >> 4;

  int srow[4], scol[4];
  #pragma unroll
  for (int i = 0; i < 4; ++i) {
    int off = wave * 4096 + i * 1024 + lane * 16;
    int row = off >> 7;                       // 128 B per row (64 bf16)
    int c16 = ((off >> 4) & 7) ^ (row & 7);   // inverse XOR swizzle
    srow[i] = row;
    scol[i] = c16 * 8;                        // in shorts
  }

  f32x4 acc[4][4] = {};
  for (int k0 = k0beg; k0 < k0beg + Kc; k0 += 64) {
    #pragma unroll
    for (int i = 0; i < 4; ++i)
      gl_lds16(A + (size_t)(m0 + srow[i]) * K + k0 + scol[i],
               &As[(wave * 4096 + i * 1024) >> 1]);
    #pragma unroll
    for (int i = 0; i < 4; ++i)
      gl_lds16(Bt + (size_t)(n0 + srow[i]) * K + k0 + scol[i],
               &Bs[(wave * 4096 + i * 1024) >> 1]);
    __syncthreads();
    #pragma unroll
    for (int t = 0; t < 2; ++t) {
      bf16x8 af[4], bfv[4];
      #pragma unroll
      for (int i = 0; i < 4; ++i) {
        int row = wr + i * 16 + fr;
        int c16 = (t * 4 + qw) ^ (row & 7);   // swizzled read
        af[i] = *(const bf16x8*)&As[row * 64 + c16 * 8];
      }
      #pragma unroll
      for (int j = 0; j < 4; ++j) {
        int row = wc + j * 16 + fr;
        int c16 = (t * 4 + qw) ^ (row & 7);
        bfv[j] = *(const bf16x8*)&Bs[row * 64 + c16 * 8];
      }
      #pragma unroll
      for (int i = 0; i < 4; ++i)
        #pragma unroll
        for (int j = 0; j < 4; ++j)
          acc[i][j] = __builtin_amdgcn_mfma_f32_16x16x32_bf16(af[i], bfv[j], acc[i][j], 0, 0, 0);
    }
    __syncthreads();
  }
  const int rr = qw * 4;
  if (mode == 1) {
    #pragma unroll
    for (int j = 0; j < 4; ++j) {
      float bj = bias[n0 + wc + j * 16 + fr];
      #pragma unroll
      for (int i = 0; i < 4; ++i)
        #pragma unroll
        for (int r = 0; r < 4; ++r) {
          float v = acc[i][j][r] + bj;
          C2[(size_t)(m0 + wr + i * 16 + rr + r) * N + (n0 + wc + j * 16 + fr)] =
              f2bf(__logf(1.f + __expf(v)));
        }
    }
  } else if (mode == 2) {
    if (n0 < 2048) {
      #pragma unroll
      for (int i = 0; i < 4; ++i)
        #pragma unroll
        for (int j = 0; j < 4; ++j)
          #pragma unroll
          for (int r = 0; r < 4; ++r)
            C[(size_t)(m0 + wr + i * 16 + rr + r) * 2048 + (n0 + wc + j * 16 + fr)] =
                acc[i][j][r];
    } else {
      #pragma unroll
      for (int i = 0; i < 4; ++i)
        #pragma unroll
        for (int j = 0; j < 4; ++j)
          #pragma unroll
          for (int r = 0; r < 4; ++r)
            C2[(size_t)(m0 + wr + i * 16 + rr + r) * 2048 + (n0 - 2048 + wc + j * 16 + fr)] =
                f2bf(acc[i][j][r]);
    }
  } else {
    #pragma unroll
    for (int i = 0; i < 4; ++i)
      #pragma unroll
      for (int j = 0; j < 4; ++j)
        #pragma unroll
        for (int r = 0; r < 4; ++r)
          Cz[(size_t)(m0 + wr + i * 16 + rr + r) * N + (n0 + wc + j * 16 + fr)] = acc[i][j][r];
  }
}

// ---------------- merged prep: x->bf16, W_in^T, W_out^T, W_dt^T, W_x pad^T ----------------
__device__ __forceinline__ void transpose_tile(
    const float* __restrict__ src, unsigned short* __restrict__ dst,
    int R, int C, int bx, int by, float* t /* [64][65] */)
{
  int bc = bx * 64, br = by * 64;
  int tr = threadIdx.x >> 2;
  int tc = (threadIdx.x & 3) * 16;
  #pragma unroll
  for (int i = 0; i < 4; ++i) {
    float4 v = *(const float4*)(src + (size_t)(br + tr) * C + bc + tc + i * 4);
    t[tr * 65 + tc + i * 4 + 0] = v.x; t[tr * 65 + tc + i * 4 + 1] = v.y;
    t[tr * 65 + tc + i * 4 + 2] = v.z; t[tr * 65 + tc + i * 4 + 3] = v.w;
  }
  __syncthreads();
  unsigned short tmp[16];
  #pragma unroll
  for (int i = 0; i < 16; ++i) tmp[i] = f2bf(t[(tc + i) * 65 + tr]);
  unsigned short* dp = dst + (size_t)(bc + tr) * R + br + tc;
  *(i32x4*)dp = *(i32x4*)&tmp[0];
  *(i32x4*)(dp + 8) = *(i32x4*)&tmp[8];
}

__global__ __launch_bounds__(256) void k_prep(
    const float* __restrict__ x,   unsigned short* __restrict__ xbf,
    const float* __restrict__ Win, unsigned short* __restrict__ wint,
    const float* __restrict__ Wout,unsigned short* __restrict__ woutt,
    const float* __restrict__ Wdt, unsigned short* __restrict__ wdtt,
    const float* __restrict__ Wx,  unsigned short* __restrict__ wxt)
{
  __shared__ float t[64 * 65];
  int bid = blockIdx.x;
  if (bid < 1024) {                       // x -> bf16 (2M elements, 8/thread)
    int i = (bid * 256 + threadIdx.x) * 8;
    float4 a = *(const float4*)(x + i);
    float4 b = *(const float4*)(x + i + 4);
    unsigned short tmp[8] = {f2bf(a.x), f2bf(a.y), f2bf(a.z), f2bf(a.w),
                             f2bf(b.x), f2bf(b.y), f2bf(b.z), f2bf(b.w)};
    *(i32x4*)(xbf + i) = *(i32x4*)tmp;
  } else if (bid < 2048) {                // W_in [1024][4096] -> [4096][1024]
    int tt = bid - 1024;
    transpose_tile(Win, wint, 1024, 4096, tt & 63, tt >> 6, t);
  } else if (bid < 2560) {                // W_out [2048][1024] -> [1024][2048]
    int tt = bid - 2048;
    transpose_tile(Wout, woutt, 2048, 1024, tt & 15, tt >> 4, t);
  } else if (bid < 2592) {                // W_dt [64][2048] -> [2048][64]
    int tt = bid - 2560;
    transpose_tile(Wdt, wdtt, 64, 2048, tt, 0, t);
  } else {                                // W_x [2048][96] -> padded [128][2048]
    int idx = (bid - 2592) * 256 + threadIdx.x;  // over 128*2048
    int k = idx & (DINNER - 1);
    int n = idx >> 11;
    float v = (n < 96) ? Wx[(size_t)k * 96 + n] : 0.f;
    wxt[idx] = f2bf(v);
  }
}

// ---------------- depthwise conv4 + bias + SiLU -> bf16 ----------------
__global__ __launch_bounds__(256) void k_conv_silu(
    const float* __restrict__ xr, const float* __restrict__ cw,
    const float* __restrict__ cb, unsigned short* __restrict__ xcb)
{
  int idx = blockIdx.x * 256 + threadIdx.x;  // over B*L*DINNER
  int d = idx & (DINNER - 1);
  int bl = idx >> 11;
  int l = bl & (SEQL - 1);
  float s = cb[d];
  #pragma unroll
  for (int k = 0; k < 4; ++k) {
    int ll = l - 3 + k;
    if (ll >= 0) s += xr[(size_t)(bl - 3 + k) * DINNER + d] * cw[d * 4 + k];
  }
  float r = s * sigmoidf_(s);
  xcb[idx] = f2bf(r);
}

// ---------------- reduce 16 split-K partials -> dbl fp32; fuse dt-col extract -> bf16 ----------------
__global__ void k_reduce2(const float* __restrict__ part, float* __restrict__ dbl,
                          unsigned short* __restrict__ dtraw)
{
  int idx = blockIdx.x * 256 + threadIdx.x;  // over 2048*128
  float s = 0.f;
  #pragma unroll
  for (int z = 0; z < 16; ++z) s += part[(size_t)z * 2048 * 128 + idx];
  dbl[idx] = s;
  int col = idx & 127, rw = idx >> 7;
  if (col < 64) dtraw[rw * 64 + col] = f2bf(s);
}

// ---------------- reduce 4 split-K partials -> out (vectorized) ----------------
__global__ void k_reduce5(const float* __restrict__ part, float* __restrict__ out)
{
  int idx = (blockIdx.x * 256 + threadIdx.x) * 4;  // over 2048*1024
  f32x4 s = *(const f32x4*)(part + idx);
  #pragma unroll
  for (int z = 1; z < 4; ++z)
    s += *(const f32x4*)(part + (size_t)z * 2048 * 1024 + idx);
  *(f32x4*)(out + idx) = s;
}

// ---------------- scan pass A: local scan; B rows via LDS broadcast; 2-step batches ----------------
__global__ __launch_bounds__(256) void k_scan_A(
    const unsigned short* __restrict__ dtb, const unsigned short* __restrict__ xcb,
    const float* __restrict__ dbl, const float* __restrict__ Alog,
    float2* __restrict__ hpair)
{
  __shared__ __attribute__((aligned(16))) float bcB[LC][DSTATE];
  int gid = blockIdx.x * 256 + threadIdx.x;  // over B*NCH*DINNER
  int d = gid & (DINNER - 1);
  int t = gid >> 11;
  int c = t & (NCH - 1);
  int b = t >> 6;
  const int r0 = b * SEQL + c * LC;
  bcB[threadIdx.x >> 4][threadIdx.x & 15] =
      dbl[(size_t)(r0 + (threadIdx.x >> 4)) * 128 + 64 + (threadIdx.x & 15)];
  float As[DSTATE];
  #pragma unroll
  for (int i = 0; i < 4; ++i) {
    f32x4 a = *(const f32x4*)&Alog[d * DSTATE + i * 4];
    #pragma unroll
    for (int j = 0; j < 4; ++j) As[i * 4 + j] = -__expf(a[j]);
  }
  __syncthreads();
  float h[DSTATE];
  #pragma unroll
  for (int s = 0; s < DSTATE; ++s) h[s] = 0.f;
  float sumdt = 0.f;
  #pragma unroll
  for (int li = 0; li < LC; li += 2) {
    float dt0 = bf2f(dtb[(size_t)(r0 + li) * DINNER + d]);
    float xv0 = bf2f(xcb[(size_t)(r0 + li) * DINNER + d]);
    float dt1 = bf2f(dtb[(size_t)(r0 + li + 1) * DINNER + d]);
    float xv1 = bf2f(xcb[(size_t)(r0 + li + 1) * DINNER + d]);
    f32x4 B0[4], B1[4];
    #pragma unroll
    for (int i = 0; i < 4; ++i) B0[i] = *(const f32x4*)&bcB[li][i * 4];
    #pragma unroll
    for (int i = 0; i < 4; ++i) B1[i] = *(const f32x4*)&bcB[li + 1][i * 4];
    float dtx0 = dt0 * xv0, dtx1 = dt1 * xv1;
    sumdt += dt0 + dt1;
    const float* Bv0 = (const float*)B0;
    const float* Bv1 = (const float*)B1;
    #pragma unroll
    for (int s = 0; s < DSTATE; ++s) {
      float dA0 = __expf(dt0 * As[s]);
      h[s] = dA0 * h[s] + dtx0 * Bv0[s];
      float dA1 = __expf(dt1 * As[s]);
      h[s] = dA1 * h[s] + dtx1 * Bv1[s];
    }
  }
  size_t base = ((size_t)(b * NCH + c) * DSTATE) * DINNER + d;
  #pragma unroll
  for (int s = 0; s < DSTATE; ++s) {
    float2 v; v.x = h[s]; v.y = __expf(sumdt * As[s]);
    hpair[base + (size_t)s * DINNER] = v;
  }
}

// ---------------- scan pass B: sequential prefix over chunks, batched loads ----------------
__global__ void k_scan_B(const float2* __restrict__ hpair, float* __restrict__ hin)
{
  int gid = blockIdx.x * 256 + threadIdx.x;  // B*DSTATE*DINNER = 65536
  int d = gid & (DINNER - 1);
  int s = (gid >> 11) & (DSTATE - 1);
  int b = gid >> 15;
  float h = 0.f;
  for (int c0 = 0; c0 < NCH; c0 += 8) {
    float2 v[8];
    #pragma unroll
    for (int i = 0; i < 8; ++i)
      v[i] = hpair[((size_t)(b * NCH + c0 + i) * DSTATE + s) * DINNER + d];
    #pragma unroll
    for (int i = 0; i < 8; ++i) {
      hin[((size_t)(b * NCH + c0 + i) * DSTATE + s) * DINNER + d] = h;
      h = v[i].y * h + v[i].x;
    }
  }
}

// ---------------- scan pass C: replay + fused epilogue; B/C rows via LDS; 2-step batches ----------------
__global__ __launch_bounds__(256) void k_scan_C(
    const unsigned short* __restrict__ dtb, const unsigned short* __restrict__ xcb,
    const float* __restrict__ dbl, const float* __restrict__ Alog,
    const float* __restrict__ hin, const float* __restrict__ Dskip,
    const unsigned short* __restrict__ zb, unsigned short* __restrict__ yact)
{
  __shared__ __attribute__((aligned(16))) float bc[LC][32];  // [step][B0..15,C0..15]
  int gid = blockIdx.x * 256 + threadIdx.x;
  int d = gid & (DINNER - 1);
  int t = gid >> 11;
  int c = t & (NCH - 1);
  int b = t >> 6;
  const int r0 = b * SEQL + c * LC;
  {
    int step = threadIdx.x >> 4, j = (threadIdx.x & 15) * 2;
    float2 v = *(const float2*)&dbl[(size_t)(r0 + step) * 128 + 64 + j];
    bc[step][j] = v.x; bc[step][j + 1] = v.y;
  }
  float As[DSTATE];
  #pragma unroll
  for (int i = 0; i < 4; ++i) {
    f32x4 a = *(const f32x4*)&Alog[d * DSTATE + i * 4];
    #pragma unroll
    for (int j = 0; j < 4; ++j) As[i * 4 + j] = -__expf(a[j]);
  }
  float h[DSTATE];
  size_t base = ((size_t)(b * NCH + c) * DSTATE) * DINNER + d;
  #pragma unroll
  for (int s = 0; s < DSTATE; ++s) h[s] = hin[base + (size_t)s * DINNER];
  const float dsk = Dskip[d];
  __syncthreads();
  #pragma unroll
  for (int li = 0; li < LC; li += 2) {
    const int r = r0 + li;
    float dt0 = bf2f(dtb[(size_t)r * DINNER + d]);
    float xv0 = bf2f(xcb[(size_t)r * DINNER + d]);
    float zv0 = bf2f(zb [(size_t)r * DINNER + d]);
    float dt1 = bf2f(dtb[(size_t)(r + 1) * DINNER + d]);
    float xv1 = bf2f(xcb[(size_t)(r + 1) * DINNER + d]);
    float zv1 = bf2f(zb [(size_t)(r + 1) * DINNER + d]);
    f32x4 B0[4], C0[4], B1[4], C1[4];
    #pragma unroll
    for (int i = 0; i < 4; ++i) B0[i] = *(const f32x4*)&bc[li][i * 4];
    #pragma unroll
    for (int i = 0; i < 4; ++i) C0[i] = *(const f32x4*)&bc[li][16 + i * 4];
    #pragma unroll
    for (int i = 0; i < 4; ++i) B1[i] = *(const f32x4*)&bc[li + 1][i * 4];
    #pragma unroll
    for (int i = 0; i < 4; ++i) C1[i] = *(const f32x4*)&bc[li + 1][16 + i * 4];
    const float* Bv0 = (const float*)B0; const float* Cv0 = (const float*)C0;
    const float* Bv1 = (const float*)B1; const float* Cv1 = (const float*)C1;
    float dtx0 = dt0 * xv0, dtx1 = dt1 * xv1;
    float y0 = 0.f, y1 = 0.f;
    #pragma unroll
    for (int s = 0; s < DSTATE; ++s) {
      float dA0 = __expf(dt0 * As[s]);
      h[s] = dA0 * h[s] + dtx0 * Bv0[s];
      y0 += h[s] * Cv0[s];
      float dA1 = __expf(dt1 * As[s]);
      h[s] = dA1 * h[s] + dtx1 * Bv1[s];
      y1 += h[s] * Cv1[s];
    }
    y0 += xv0 * dsk;
    y1 += xv1 * dsk;
    float ya0 = y0 * (zv0 * sigmoidf_(zv0));
    float ya1 = y1 * (zv1 * sigmoidf_(zv1));
    yact[(size_t)r * DINNER + d] = f2bf(ya0);
    yact[(size_t)(r + 1) * DINNER + d] = f2bf(ya1);
  }
}

extern "C" void kernel_launch(void* const* d_in, const int* in_sizes, int n_in,
                              void* d_out, int out_size, void* d_ws, size_t ws_size,
                              hipStream_t stream) {
  const float* x     = (const float*)d_in[0];
  const float* Win   = (const float*)d_in[1];
  const float* cw    = (const float*)d_in[2];
  const float* cbias = (const float*)d_in[3];
  const float* Wx    = (const float*)d_in[4];
  const float* Wdt   = (const float*)d_in[5];
  const float* bdt   = (const float*)d_in[6];
  const float* Alog  = (const float*)d_in[7];
  const float* Dsk   = (const float*)d_in[8];
  const float* Wout  = (const float*)d_in[9];
  float* out = (float*)d_out;

  char* ws = (char*)d_ws;
  const size_t MB = 1 << 20;
  // layout, CORRECT sizes (hpair = 32 MB, hin = 16 MB; total 116 MB < 146 MB proven in r5)
  float*          xr    = (float*)         (ws);               // 16 MB   dead after conv
  unsigned short* xbf   = (unsigned short*)(ws + 16 * MB);     //  4 MB   dead after GEMM1
  unsigned short* wint  = (unsigned short*)(ws + 20 * MB);     //  8 MB   dead after GEMM1
  unsigned short* xcb   = (unsigned short*)(ws + 28 * MB);     //  8 MB   dead after scan_C
  unsigned short* wxt   = (unsigned short*)(ws + 36 * MB);     //  0.5 MB dead after GEMM2
  float*          dbl   = (float*)         (ws + 37 * MB);     //  1 MB   dead after scan_C
  unsigned short* dtraw = (unsigned short*)(ws + 38 * MB);     //  0.25   dead after GEMM3
  unsigned short* wdtt  = (unsigned short*)(ws + 39 * MB);     //  0.25   dead after GEMM3
  unsigned short* dtb16 = (unsigned short*)(ws + 40 * MB);     //  8 MB   dead after scan_C
  unsigned short* zb    = (unsigned short*)(ws + 48 * MB);     //  8 MB   dead after scan_C
  float2*         hpair = (float2*)        (ws + 56 * MB);     // 32 MB   dead after scan_B
  float*          hin   = (float*)         (ws + 88 * MB);     // 16 MB   dead after scan_C
  unsigned short* yact  = (unsigned short*)(ws + 104 * MB);    //  8 MB   dead after GEMM5
  unsigned short* woutt = (unsigned short*)(ws + 112 * MB);    //  4 MB   dead after GEMM5
  // aliases (strictly sequential lifetimes on one stream):
  float* part2 = (float*)(ws);   // 16 x 1 MB = 16 MB over dead xr (GEMM2 runs after conv)
  float* part5 = (float*)(ws);   // 4 x 8 MB = 32 MB over dead xr+xbf+wint+xcb[0:4MB]
  (void)ws_size; (void)in_sizes; (void)n_in; (void)out_size;

  // merged prep: x->bf16 | W_in^T | W_out^T | W_dt^T | W_x pad^T
  k_prep<<<3616, 256, 0, stream>>>(x, xbf, Win, wint, Wout, woutt, Wdt, wdtt, Wx, wxt);
  // GEMM1 (mode 2): xr(fp32) | zb(bf16) = x @ W_in   (M=2048, N=4096, K=1024)
  k_gemm_mfma<<<dim3(16, 32, 1), 256, 0, stream>>>(xbf, wint, xr, zb, 2048, 4096, 1024, nullptr, 2);
  // conv + SiLU -> bf16 only
  k_conv_silu<<<16384, 256, 0, stream>>>(xr, cw, cbias, xcb);
  // GEMM2: part2[z] = xc @ W_x_pad (K-slice z)  (M=2048, N=128, K=2048, split 16)
  k_gemm_mfma<<<dim3(16, 1, 16), 256, 0, stream>>>(xcb, wxt, part2, nullptr, 2048, 128, 2048, nullptr, 0);
  // reduce partials -> dbl fp32; fused dt-col extract -> bf16
  k_reduce2<<<1024, 256, 0, stream>>>(part2, dbl, dtraw);
  // GEMM3 (mode 1): dtb16 = bf16(softplus(dt_raw @ W_dt + b_dt))  (M=2048, N=2048, K=64)
  k_gemm_mfma<<<dim3(16, 16, 1), 256, 0, stream>>>(dtraw, wdtt, nullptr, dtb16, 2048, 2048, 64, bdt, 1);
  // chunked scan
  k_scan_A<<<1024, 256, 0, stream>>>(dtb16, xcb, dbl, Alog, hpair);
  k_scan_B<<<256, 256, 0, stream>>>(hpair, hin);
  k_scan_C<<<1024, 256, 0, stream>>>(dtb16, xcb, dbl, Alog, hin, Dsk, zb, yact);
  // GEMM5: part5[z] = y_act @ W_out (K-slice z)  (M=2048, N=1024, K=2048, split 4)
  k_gemm_mfma<<<dim3(16, 8, 4), 256, 0, stream>>>(yact, woutt, part5, nullptr, 2048, 1024, 2048, nullptr, 0);
  // reduce partials -> out
  k_reduce5<<<2048, 256, 0, stream>>>(part5, out);
}